// Round 1
// baseline (58982.605 us; speedup 1.0000x reference)
//
#include <hip/hip_runtime.h>
#include <hip/hip_cooperative_groups.h>

namespace cg = cooperative_groups;

#define TOT   3800
#define BB    8
#define TT    1000
#define AL    0.1f

constexpr int WT_FLOATS = 4475136;   // sum of padded region blocks
constexpr int NWG       = 242;

// region order: D1, D2, FSI, GPE, STN, SNR, THAL, ALM, (ITI handled separately)
__constant__ int   kWgStart[10]   = {0,33,66,76,109,142,175,208,241,242};
__constant__ int   kRowBase[9]    = {0,520,1040,1196,1716,2236,2756,3276,3796};
__constant__ int   kRowCnt[9]     = {520,520,156,520,520,520,520,520,4};
__constant__ int   kCols[8]       = {2236,2236,1200,520,520,1040,520,1040};
__constant__ int   kWtOff[8]      = {0,1180608,2361216,2553216,2827776,3102336,3651456,3926016};
__constant__ int   kWtEnd[8]      = {1180608,2361216,2553216,2827776,3102336,3651456,3926016,4475136};
__constant__ float kTonic[8]      = {0.01f,0.01f,0.01f,0.8f,0.6f,0.8f,0.01f,0.01f};
// staging segments: packed-col ranges -> global h columns
__constant__ int   kSegStart[8][3]= {{0,2756,0},{0,2756,0},{1040,2756,3796},{520,0,0},{1196,0,0},{0,1716,0},{2236,0,0},{2756,0,0}};
__constant__ int   kSegLen[8][3]  = {{1196,1040,0},{1196,1040,0},{156,1040,4},{520,0,0},{520,0,0},{520,520,0},{520,0,0},{1040,0,0}};

struct Params {
  const float *d12d1,*d22d2,*d12d2,*d22d1,*thal2alm,*thal2d1,*thal2d2,*alm2alm,
              *alm2d1,*alm2d2,*d12snr,*d22gpe,*gpe2stn,*stn2snr,*snr2thal,
              *fsi2d1,*fsi2d2,*thal2fsi,*alm2fsi,*iti2fsi,*fsi2fsi;
  const int* mask;
};

__device__ __forceinline__ float rl(float x) { return fmaxf(x, 0.0f); }

// Build packed, pre-masked, pre-signed, ALPHA-scaled W.
// Layout per region: offset = (ugg*cols + col)*4 + j, row = ugg*4 + j
__global__ void prep_wt(Params P, float* __restrict__ Wt) {
  int e = blockIdx.x * blockDim.x + threadIdx.x;
  if (e >= WT_FLOATS) return;
  int r = 0;
  while (e >= kWtEnd[r]) ++r;
  int base  = (r == 0) ? 0 : kWtEnd[r-1];
  int local = e - base;
  int j    = local & 3;
  int q    = local >> 2;
  int cols = kCols[r];
  int col  = q % cols;
  int ugg  = q / cols;
  int row  = ugg * 4 + j;
  float v = 0.0f;
  if (row < kRowCnt[r]) {
    int c = col;
    switch (r) {
      case 0: case 1: {
        const float* pd1 = (r==0) ? P.d12d1 : P.d12d2;
        const float* pd2 = (r==0) ? P.d22d1 : P.d22d2;
        const float* pf  = (r==0) ? P.fsi2d1 : P.fsi2d2;
        const float* pt  = (r==0) ? P.thal2d1 : P.thal2d2;
        const float* pa  = (r==0) ? P.alm2d1 : P.alm2d2;
        if (c < 520)       { v = -(float)P.mask[row*520+c] * rl(pd1[row*520+c]); }
        else if (c < 1040) { int cc=c-520;  v = -(float)P.mask[row*520+cc] * rl(pd2[row*520+cc]); }
        else if (c < 1196) { int cc=c-1040; v = -rl(pf[row*156+cc]); }
        else if (c < 1716) { int cc=c-1196; v =  rl(pt[row*520+cc]); }
        else               { int cc=c-1716; v = (cc<364) ? rl(pa[row*520+cc]) : 0.0f; }
        break;
      }
      case 2: {
        if (c < 156)       { v = -rl(P.fsi2fsi[row*156+c]); }
        else if (c < 676)  { int cc=c-156; v = rl(P.thal2fsi[row*520+cc]); }
        else if (c < 1196) { int cc=c-676; v = (cc<364) ? rl(P.alm2fsi[row*520+cc]) : 0.0f; }
        else               { int cc=c-1196; v = rl(P.iti2fsi[row*4+cc]); }
        break;
      }
      case 3: v = ((row<260)==(c<260)) ? -rl(P.d22gpe[row*520+c])  : 0.0f; break;
      case 4: v = ((row<260)==(c<260)) ? -rl(P.gpe2stn[row*520+c]) : 0.0f; break;
      case 5: {
        if (c < 520) { v = ((row<260)==(c<260)) ? -rl(P.d12snr[row*520+c]) : 0.0f; }
        else { int cc=c-520; v = ((row<260)==(cc<260)) ? rl(P.stn2snr[row*520+cc]) : 0.0f; }
        break;
      }
      case 6: v = ((row<260)==(c<260)) ? -rl(P.snr2thal[row*520+c]) : 0.0f; break;
      case 7: {
        if (c < 520) { v = rl(P.thal2alm[row*520+c]); }
        else { int cc=c-520; v = rl(P.alm2alm[row*520+cc]) * ((cc<364) ? 1.0f : -1.0f); }
        break;
      }
    }
    v *= AL;
  }
  Wt[e] = v;
}

// hT[u][b] = hn[b][u]
__global__ void init_h(const float* __restrict__ hn, float* __restrict__ h0) {
  int i = blockIdx.x * blockDim.x + threadIdx.x;
  if (i < TOT * BB) {
    int u = i >> 3, b = i & 7;
    h0[i] = hn[b * TOT + u];
  }
}

__global__ void __launch_bounds__(256, 1)
rnn_scan(const float* __restrict__ Wt, const float* __restrict__ noise,
         const float* __restrict__ inp, float* __restrict__ out,
         float* __restrict__ h0, float* __restrict__ h1) {
  cg::grid_group grid = cg::this_grid();
  __shared__ float s_h[2236 * 9];   // 80,496 B; stride-9 pad -> <=2-way bank conflicts
  const int bid = blockIdx.x, tid = threadIdx.x;
  int r = 0;
  while (bid >= kWgStart[r + 1]) ++r;

  if (r < 8) {
    const int wgl     = bid - kWgStart[r];
    const int cols    = kCols[r];
    const int rowcnt  = kRowCnt[r];
    const int rowbase = kRowBase[r];
    const int ug = tid >> 6, b = (tid >> 3) & 7, s = tid & 7;
    const int L  = (cols + 7) >> 3;
    const int c0 = s * L, c1 = min(cols, c0 + L);
    const float* wtp = Wt + kWtOff[r] + (size_t)(wgl * 4 + ug) * cols * 4;
    const float ton = kTonic[r];
    const int l0 = kSegLen[r][0], l1 = kSegLen[r][1];
    const int g0 = kSegStart[r][0], g1 = kSegStart[r][1], g2 = kSegStart[r][2];
    const int rowl0 = wgl * 16 + ug * 4;
    const bool lead = (s == 0);

    for (int t = 0; t < TT; ++t) {
      const float* __restrict__ hc = (t & 1) ? h1 : h0;
      float*       __restrict__ hx = (t & 1) ? h0 : h1;

      // prefetch epilogue operands early (hide HBM latency under stage+compute)
      float nz[4], hp[4];
      if (lead) {
        #pragma unroll
        for (int jj = 0; jj < 4; ++jj) {
          int rowl = rowl0 + jj;
          if (rowl < rowcnt) {
            int rg = rowbase + rowl;
            nz[jj] = noise[((size_t)b * TT + t) * TOT + rg];
            hp[jj] = hc[rg * 8 + b];
          } else { nz[jj] = 0.0f; hp[jj] = 0.0f; }
        }
      }

      // stage this region's input columns (all 8 batches) into LDS
      for (int i = tid; i < cols * 8; i += 256) {
        int c = i >> 3, bb = i & 7;
        int g;
        if (c < l0)           g = g0 + c;
        else if (c < l0 + l1) g = g1 + (c - l0);
        else                  g = g2 + (c - l0 - l1);
        s_h[c * 9 + bb] = hc[(g << 3) + bb];
      }
      __syncthreads();

      // register-blocked dot: 1 float4 W load + 1 LDS read -> 4 FMAs
      float a0 = 0.f, a1 = 0.f, a2 = 0.f, a3 = 0.f;
      #pragma unroll 4
      for (int c = c0; c < c1; ++c) {
        const float4 w = *reinterpret_cast<const float4*>(wtp + (size_t)c * 4);
        const float h = s_h[c * 9 + b];
        a0 = fmaf(w.x, h, a0); a1 = fmaf(w.y, h, a1);
        a2 = fmaf(w.z, h, a2); a3 = fmaf(w.w, h, a3);
      }
      // reduce the 8 column-splits (lanes s=0..7 adjacent)
      a0 += __shfl_xor(a0, 1); a0 += __shfl_xor(a0, 2); a0 += __shfl_xor(a0, 4);
      a1 += __shfl_xor(a1, 1); a1 += __shfl_xor(a1, 2); a1 += __shfl_xor(a1, 4);
      a2 += __shfl_xor(a2, 1); a2 += __shfl_xor(a2, 2); a2 += __shfl_xor(a2, 4);
      a3 += __shfl_xor(a3, 1); a3 += __shfl_xor(a3, 2); a3 += __shfl_xor(a3, 4);

      if (lead) {
        float acc[4] = {a0, a1, a2, a3};
        #pragma unroll
        for (int jj = 0; jj < 4; ++jj) {
          int rowl = rowl0 + jj;
          if (rowl < rowcnt) {
            int rg = rowbase + rowl;
            float x = fmaf(0.9f, hp[jj], acc[jj] + AL * (ton + nz[jj]));
            x = fmaxf(x, 0.0f);
            hx[rg * 8 + b] = x;
            out[((size_t)b * TT + t) * TOT + rg] = x;
          }
        }
      }
      grid.sync();
    }
  } else {
    // ITI workgroup: 4 units, no recurrent input, tonic = 0, gets cue input
    for (int t = 0; t < TT; ++t) {
      const float* hc = (t & 1) ? h1 : h0;
      float*       hx = (t & 1) ? h0 : h1;
      if (tid < 32) {
        int b = tid >> 2, k = tid & 3;
        int rg = 3796 + k;
        float hp = hc[rg * 8 + b];
        float nz = noise[((size_t)b * TT + t) * TOT + rg];
        float ii = inp[((size_t)b * TT + t) * 4 + k];
        float x = fmaxf(fmaf(0.9f, hp, AL * (nz + ii)), 0.0f);
        hx[rg * 8 + b] = x;
        out[((size_t)b * TT + t) * TOT + rg] = x;
      }
      grid.sync();
    }
  }
}

extern "C" void kernel_launch(void* const* d_in, const int* in_sizes, int n_in,
                              void* d_out, int out_size, void* d_ws, size_t ws_size,
                              hipStream_t stream) {
  Params P;
  P.d12d1   = (const float*)d_in[0];  P.d22d2   = (const float*)d_in[1];
  P.d12d2   = (const float*)d_in[2];  P.d22d1   = (const float*)d_in[3];
  P.thal2alm= (const float*)d_in[4];  P.thal2d1 = (const float*)d_in[5];
  P.thal2d2 = (const float*)d_in[6];  P.alm2alm = (const float*)d_in[7];
  P.alm2d1  = (const float*)d_in[8];  P.alm2d2  = (const float*)d_in[9];
  P.d12snr  = (const float*)d_in[10]; P.d22gpe  = (const float*)d_in[11];
  P.gpe2stn = (const float*)d_in[12]; P.stn2snr = (const float*)d_in[13];
  P.snr2thal= (const float*)d_in[14]; P.fsi2d1  = (const float*)d_in[15];
  P.fsi2d2  = (const float*)d_in[16]; P.thal2fsi= (const float*)d_in[17];
  P.alm2fsi = (const float*)d_in[18]; P.iti2fsi = (const float*)d_in[19];
  P.fsi2fsi = (const float*)d_in[20]; P.mask    = (const int*)d_in[21];
  const float* inp   = (const float*)d_in[22];
  const float* hn    = (const float*)d_in[23];
  const float* noise = (const float*)d_in[24];

  float* ws = (float*)d_ws;
  float* Wt = ws;
  float* h0 = ws + WT_FLOATS;
  float* h1 = h0 + TOT * BB;

  hipLaunchKernelGGL(prep_wt, dim3((WT_FLOATS + 255) / 256), dim3(256), 0, stream, P, Wt);
  hipLaunchKernelGGL(init_h,  dim3((TOT * BB + 255) / 256),  dim3(256), 0, stream, hn, h0);

  const float* WtA = Wt; const float* noiseA = noise; const float* inpA = inp;
  float* outA = (float*)d_out; float* h0A = h0; float* h1A = h1;
  void* kargs[6] = {&WtA, &noiseA, &inpA, &outA, &h0A, &h1A};
  hipLaunchCooperativeKernel((const void*)rnn_scan, dim3(NWG), dim3(256), kargs, 0, stream);
}

// Round 2
// 37364.859 us; speedup vs baseline: 1.5786x; 1.5786x over previous
//
#include <hip/hip_runtime.h>
#include <hip/hip_cooperative_groups.h>

namespace cg = cooperative_groups;

#define TOT   3800
#define BB    8
#define TT    1000
#define AL    0.1f

constexpr int WT_FLOATS = 4475136;   // sum of padded region blocks
constexpr int NWG       = 242;

// region order: D1, D2, FSI, GPE, STN, SNR, THAL, ALM, (ITI handled separately)
__constant__ int   kWgStart[10]   = {0,33,66,76,109,142,175,208,241,242};
__constant__ int   kRowBase[9]    = {0,520,1040,1196,1716,2236,2756,3276,3796};
__constant__ int   kRowCnt[9]     = {520,520,156,520,520,520,520,520,4};
__constant__ int   kCols[8]       = {2236,2236,1200,520,520,1040,520,1040};
__constant__ int   kWtOff[8]      = {0,1180608,2361216,2553216,2827776,3102336,3651456,3926016};
__constant__ int   kWtEnd[8]      = {1180608,2361216,2553216,2827776,3102336,3651456,3926016,4475136};
__constant__ float kTonic[8]      = {0.01f,0.01f,0.01f,0.8f,0.6f,0.8f,0.01f,0.01f};
// staging segments: packed-col ranges -> global h columns
__constant__ int   kSegStart[8][3]= {{0,2756,0},{0,2756,0},{1040,2756,3796},{520,0,0},{1196,0,0},{0,1716,0},{2236,0,0},{2756,0,0}};
__constant__ int   kSegLen[8][3]  = {{1196,1040,0},{1196,1040,0},{156,1040,4},{520,0,0},{520,0,0},{520,520,0},{520,0,0},{1040,0,0}};

struct Params {
  const float *d12d1,*d22d2,*d12d2,*d22d1,*thal2alm,*thal2d1,*thal2d2,*alm2alm,
              *alm2d1,*alm2d2,*d12snr,*d22gpe,*gpe2stn,*stn2snr,*snr2thal,
              *fsi2d1,*fsi2d2,*thal2fsi,*alm2fsi,*iti2fsi,*fsi2fsi;
  const int* mask;
};

__device__ __forceinline__ float rl(float x) { return fmaxf(x, 0.0f); }

// Build packed, pre-masked, pre-signed, ALPHA-scaled W.
// Layout per region: offset = (ugg*cols + col)*4 + j, row = ugg*4 + j
__global__ void prep_wt(Params P, float* __restrict__ Wt) {
  int e = blockIdx.x * blockDim.x + threadIdx.x;
  if (e >= WT_FLOATS) return;
  int r = 0;
  while (e >= kWtEnd[r]) ++r;
  int base  = (r == 0) ? 0 : kWtEnd[r-1];
  int local = e - base;
  int j    = local & 3;
  int q    = local >> 2;
  int cols = kCols[r];
  int col  = q % cols;
  int ugg  = q / cols;
  int row  = ugg * 4 + j;
  float v = 0.0f;
  if (row < kRowCnt[r]) {
    int c = col;
    switch (r) {
      case 0: case 1: {
        const float* pd1 = (r==0) ? P.d12d1 : P.d12d2;
        const float* pd2 = (r==0) ? P.d22d1 : P.d22d2;
        const float* pf  = (r==0) ? P.fsi2d1 : P.fsi2d2;
        const float* pt  = (r==0) ? P.thal2d1 : P.thal2d2;
        const float* pa  = (r==0) ? P.alm2d1 : P.alm2d2;
        if (c < 520)       { v = -(float)P.mask[row*520+c] * rl(pd1[row*520+c]); }
        else if (c < 1040) { int cc=c-520;  v = -(float)P.mask[row*520+cc] * rl(pd2[row*520+cc]); }
        else if (c < 1196) { int cc=c-1040; v = -rl(pf[row*156+cc]); }
        else if (c < 1716) { int cc=c-1196; v =  rl(pt[row*520+cc]); }
        else               { int cc=c-1716; v = (cc<364) ? rl(pa[row*520+cc]) : 0.0f; }
        break;
      }
      case 2: {
        if (c < 156)       { v = -rl(P.fsi2fsi[row*156+c]); }
        else if (c < 676)  { int cc=c-156; v = rl(P.thal2fsi[row*520+cc]); }
        else if (c < 1196) { int cc=c-676; v = (cc<364) ? rl(P.alm2fsi[row*520+cc]) : 0.0f; }
        else               { int cc=c-1196; v = rl(P.iti2fsi[row*4+cc]); }
        break;
      }
      case 3: v = ((row<260)==(c<260)) ? -rl(P.d22gpe[row*520+c])  : 0.0f; break;
      case 4: v = ((row<260)==(c<260)) ? -rl(P.gpe2stn[row*520+c]) : 0.0f; break;
      case 5: {
        if (c < 520) { v = ((row<260)==(c<260)) ? -rl(P.d12snr[row*520+c]) : 0.0f; }
        else { int cc=c-520; v = ((row<260)==(cc<260)) ? rl(P.stn2snr[row*520+cc]) : 0.0f; }
        break;
      }
      case 6: v = ((row<260)==(c<260)) ? -rl(P.snr2thal[row*520+c]) : 0.0f; break;
      case 7: {
        if (c < 520) { v = rl(P.thal2alm[row*520+c]); }
        else { int cc=c-520; v = rl(P.alm2alm[row*520+cc]) * ((cc<364) ? 1.0f : -1.0f); }
        break;
      }
    }
    v *= AL;
  }
  Wt[e] = v;
}

// hT[u][b] = hn[b][u]
__global__ void init_h(const float* __restrict__ hn, float* __restrict__ h0) {
  int i = blockIdx.x * blockDim.x + threadIdx.x;
  if (i < TOT * BB) {
    int u = i >> 3, b = i & 7;
    h0[i] = hn[b * TOT + u];
  }
}

// 1024 threads/WG = 16 waves/CU (4/SIMD). W held in registers across all steps.
// Thread = (rg = tid>>8 : 4-row group, sp = tid&255 : column split).
// Columns interleaved: c = sp + 256*i, i<9 -> conflict-free LDS reads.
__global__ void __launch_bounds__(1024, 4)
rnn_scan(const float* __restrict__ Wt, const float* __restrict__ noise,
         const float* __restrict__ inp, float* __restrict__ out,
         float* __restrict__ h0, float* __restrict__ h1) {
  cg::grid_group grid = cg::this_grid();
  __shared__ float S[33280];   // union: h as [b][c] stride 2308 (18464 f) / partials [128][260] (33280 f)
  const int bid = blockIdx.x, tid = threadIdx.x;
  int r = 0;
  while (bid >= kWgStart[r + 1]) ++r;

  if (r < 8) {
    const int wgl     = bid - kWgStart[r];
    const int cols    = kCols[r];
    const int rowcnt  = kRowCnt[r];
    const int rowbase = kRowBase[r];
    const int rg = tid >> 8, sp = tid & 255;
    const int ugg = wgl * 4 + rg;
    const float* wtp = Wt + kWtOff[r] + (size_t)ugg * cols * 4;
    const float ton = kTonic[r];
    const int l0 = kSegLen[r][0], l1 = kSegLen[r][1];
    const int g0 = kSegStart[r][0], g1 = kSegStart[r][1], g2 = kSegStart[r][2];

    // ---- load this thread's W fragment into registers (persists across all 1000 steps)
    float4 w[9];
    #pragma unroll
    for (int i = 0; i < 9; ++i) {
      int c = sp + (i << 8);
      if (c < cols) w[i] = *reinterpret_cast<const float4*>(wtp + (size_t)c * 4);
      else          w[i] = make_float4(0.f, 0.f, 0.f, 0.f);
    }

    // ---- epilogue role: threads with (tid&7)==0 own output o = tid>>3 = (row,b)
    const int  j     = tid & 7;
    const int  o     = tid >> 3;          // 0..127
    const int  erow  = o >> 3, eb = o & 7;
    const int  erowl = wgl * 16 + erow;
    const bool ewr   = (j == 0) && (erowl < rowcnt);
    const int  erg   = rowbase + erowl;

    for (int t = 0; t < TT; ++t) {
      const float* __restrict__ hc = (t & 1) ? h1 : h0;
      float*       __restrict__ hx = (t & 1) ? h0 : h1;

      // prefetch epilogue operands (latency hidden under stage+compute)
      float hp = 0.f, nz = 0.f;
      if (ewr) {
        nz = noise[((size_t)eb * TT + t) * TOT + erg];
        hp = hc[erg * 8 + eb];
      }

      // stage h transposed: S[b*2308 + c], c in [0,2304), zero-padded past cols
      for (int i = tid; i < 2304 * 8; i += 1024) {
        int c = i >> 3, bb = i & 7;
        float v = 0.f;
        if (c < cols) {
          int g;
          if (c < l0)           g = g0 + c;
          else if (c < l0 + l1) g = g1 + (c - l0);
          else                  g = g2 + (c - l0 - l1);
          v = hc[(g << 3) + bb];
        }
        S[bb * 2308 + c] = v;
      }
      __syncthreads();

      // FMA burst: 72 conflict-free ds_read_b32 + 288 fmaf per thread
      float acc[4][8];
      #pragma unroll
      for (int r2 = 0; r2 < 4; ++r2)
        #pragma unroll
        for (int b = 0; b < 8; ++b) acc[r2][b] = 0.f;

      #pragma unroll
      for (int i = 0; i < 9; ++i) {
        const float4 wv = w[i];
        const int c = sp + (i << 8);
        #pragma unroll
        for (int b = 0; b < 8; ++b) {
          const float h = S[b * 2308 + c];
          acc[0][b] = fmaf(wv.x, h, acc[0][b]);
          acc[1][b] = fmaf(wv.y, h, acc[1][b]);
          acc[2][b] = fmaf(wv.z, h, acc[2][b]);
          acc[3][b] = fmaf(wv.w, h, acc[3][b]);
        }
      }
      __syncthreads();   // done reading h; reuse S for partials

      // partials: S[((rg*4+r)*8+b)*260 + sp]  (stride 260 -> ~2-way on read)
      #pragma unroll
      for (int r2 = 0; r2 < 4; ++r2)
        #pragma unroll
        for (int b = 0; b < 8; ++b)
          S[((rg * 4 + r2) * 8 + b) * 260 + sp] = acc[r2][b];
      __syncthreads();

      // reduce 256 splits: thread (o,j) sums sp = j+8k, then 3x shfl_xor over j
      float s = 0.f;
      #pragma unroll
      for (int k = 0; k < 32; ++k) s += S[o * 260 + j + (k << 3)];
      s += __shfl_xor(s, 1);
      s += __shfl_xor(s, 2);
      s += __shfl_xor(s, 4);

      if (ewr) {
        float x = fmaf(0.9f, hp, s + AL * (ton + nz));
        x = fmaxf(x, 0.0f);
        hx[erg * 8 + eb] = x;
        out[((size_t)eb * TT + t) * TOT + erg] = x;
      }
      grid.sync();
    }
  } else {
    // ITI workgroup: 4 units, no recurrent input, tonic = 0, gets cue input
    for (int t = 0; t < TT; ++t) {
      const float* hc = (t & 1) ? h1 : h0;
      float*       hx = (t & 1) ? h0 : h1;
      if (tid < 32) {
        int b = tid >> 2, k = tid & 3;
        int rg2 = 3796 + k;
        float hp = hc[rg2 * 8 + b];
        float nz = noise[((size_t)b * TT + t) * TOT + rg2];
        float ii = inp[((size_t)b * TT + t) * 4 + k];
        float x = fmaxf(fmaf(0.9f, hp, AL * (nz + ii)), 0.0f);
        hx[rg2 * 8 + b] = x;
        out[((size_t)b * TT + t) * TOT + rg2] = x;
      }
      grid.sync();
    }
  }
}

extern "C" void kernel_launch(void* const* d_in, const int* in_sizes, int n_in,
                              void* d_out, int out_size, void* d_ws, size_t ws_size,
                              hipStream_t stream) {
  Params P;
  P.d12d1   = (const float*)d_in[0];  P.d22d2   = (const float*)d_in[1];
  P.d12d2   = (const float*)d_in[2];  P.d22d1   = (const float*)d_in[3];
  P.thal2alm= (const float*)d_in[4];  P.thal2d1 = (const float*)d_in[5];
  P.thal2d2 = (const float*)d_in[6];  P.alm2alm = (const float*)d_in[7];
  P.alm2d1  = (const float*)d_in[8];  P.alm2d2  = (const float*)d_in[9];
  P.d12snr  = (const float*)d_in[10]; P.d22gpe  = (const float*)d_in[11];
  P.gpe2stn = (const float*)d_in[12]; P.stn2snr = (const float*)d_in[13];
  P.snr2thal= (const float*)d_in[14]; P.fsi2d1  = (const float*)d_in[15];
  P.fsi2d2  = (const float*)d_in[16]; P.thal2fsi= (const float*)d_in[17];
  P.alm2fsi = (const float*)d_in[18]; P.iti2fsi = (const float*)d_in[19];
  P.fsi2fsi = (const float*)d_in[20]; P.mask    = (const int*)d_in[21];
  const float* inp   = (const float*)d_in[22];
  const float* hn    = (const float*)d_in[23];
  const float* noise = (const float*)d_in[24];

  float* ws = (float*)d_ws;
  float* Wt = ws;
  float* h0 = ws + WT_FLOATS;
  float* h1 = h0 + TOT * BB;

  hipLaunchKernelGGL(prep_wt, dim3((WT_FLOATS + 255) / 256), dim3(256), 0, stream, P, Wt);
  hipLaunchKernelGGL(init_h,  dim3((TOT * BB + 255) / 256),  dim3(256), 0, stream, hn, h0);

  const float* WtA = Wt; const float* noiseA = noise; const float* inpA = inp;
  float* outA = (float*)d_out; float* h0A = h0; float* h1A = h1;
  void* kargs[6] = {&WtA, &noiseA, &inpA, &outA, &h0A, &h1A};
  hipLaunchCooperativeKernel((const void*)rnn_scan, dim3(NWG), dim3(1024), kargs, 0, stream);
}

// Round 3
// 19838.275 us; speedup vs baseline: 2.9732x; 1.8835x over previous
//
#include <hip/hip_runtime.h>

#define TOT   3800
#define BB    8
#define TT    1000
#define AL    0.1f

constexpr int WT_FLOATS = 4475136;   // sum of padded region blocks
constexpr int NWG       = 241;       // ITI folded into FSI wg 9's padded rows

// region order: D1, D2, FSI(+ITI), GPE, STN, SNR, THAL, ALM
__constant__ int   kWgStart[9]    = {0,33,66,76,109,142,175,208,241};
__constant__ int   kRowBase[8]    = {0,520,1040,1196,1716,2236,2756,3276};
__constant__ int   kRowCnt[8]     = {520,520,156,520,520,520,520,520};
__constant__ int   kCols[8]       = {2236,2236,1200,520,520,1040,520,1040};
__constant__ int   kWtOff[8]      = {0,1180608,2361216,2553216,2827776,3102336,3651456,3926016};
__constant__ int   kWtEnd[8]      = {1180608,2361216,2553216,2827776,3102336,3651456,3926016,4475136};
__constant__ float kTonic[8]      = {0.01f,0.01f,0.01f,0.8f,0.6f,0.8f,0.01f,0.01f};
// staging segments: packed-col ranges -> global h columns
__constant__ int   kSegStart[8][3]= {{0,2756,0},{0,2756,0},{1040,2756,3796},{520,0,0},{1196,0,0},{0,1716,0},{2236,0,0},{2756,0,0}};
__constant__ int   kSegLen[8][3]  = {{1196,1040,0},{1196,1040,0},{156,1040,4},{520,0,0},{520,0,0},{520,520,0},{520,0,0},{1040,0,0}};

struct Params {
  const float *d12d1,*d22d2,*d12d2,*d22d1,*thal2alm,*thal2d1,*thal2d2,*alm2alm,
              *alm2d1,*alm2d2,*d12snr,*d22gpe,*gpe2stn,*stn2snr,*snr2thal,
              *fsi2d1,*fsi2d2,*thal2fsi,*alm2fsi,*iti2fsi,*fsi2fsi;
  const int* mask;
};

__device__ __forceinline__ float rl(float x) { return fmaxf(x, 0.0f); }

// Build packed, pre-masked, pre-signed, ALPHA-scaled W.
// Layout per region: offset = (ugg*cols + col)*4 + j, row = ugg*4 + j
__global__ void prep_wt(Params P, float* __restrict__ Wt) {
  int e = blockIdx.x * blockDim.x + threadIdx.x;
  if (e >= WT_FLOATS) return;
  int r = 0;
  while (e >= kWtEnd[r]) ++r;
  int base  = (r == 0) ? 0 : kWtEnd[r-1];
  int local = e - base;
  int j    = local & 3;
  int q    = local >> 2;
  int cols = kCols[r];
  int col  = q % cols;
  int ugg  = q / cols;
  int row  = ugg * 4 + j;
  float v = 0.0f;
  if (row < kRowCnt[r]) {
    int c = col;
    switch (r) {
      case 0: case 1: {
        const float* pd1 = (r==0) ? P.d12d1 : P.d12d2;
        const float* pd2 = (r==0) ? P.d22d1 : P.d22d2;
        const float* pf  = (r==0) ? P.fsi2d1 : P.fsi2d2;
        const float* pt  = (r==0) ? P.thal2d1 : P.thal2d2;
        const float* pa  = (r==0) ? P.alm2d1 : P.alm2d2;
        if (c < 520)       { v = -(float)P.mask[row*520+c] * rl(pd1[row*520+c]); }
        else if (c < 1040) { int cc=c-520;  v = -(float)P.mask[row*520+cc] * rl(pd2[row*520+cc]); }
        else if (c < 1196) { int cc=c-1040; v = -rl(pf[row*156+cc]); }
        else if (c < 1716) { int cc=c-1196; v =  rl(pt[row*520+cc]); }
        else               { int cc=c-1716; v = (cc<364) ? rl(pa[row*520+cc]) : 0.0f; }
        break;
      }
      case 2: {
        if (c < 156)       { v = -rl(P.fsi2fsi[row*156+c]); }
        else if (c < 676)  { int cc=c-156; v = rl(P.thal2fsi[row*520+cc]); }
        else if (c < 1196) { int cc=c-676; v = (cc<364) ? rl(P.alm2fsi[row*520+cc]) : 0.0f; }
        else               { int cc=c-1196; v = rl(P.iti2fsi[row*4+cc]); }
        break;
      }
      case 3: v = ((row<260)==(c<260)) ? -rl(P.d22gpe[row*520+c])  : 0.0f; break;
      case 4: v = ((row<260)==(c<260)) ? -rl(P.gpe2stn[row*520+c]) : 0.0f; break;
      case 5: {
        if (c < 520) { v = ((row<260)==(c<260)) ? -rl(P.d12snr[row*520+c]) : 0.0f; }
        else { int cc=c-520; v = ((row<260)==(cc<260)) ? rl(P.stn2snr[row*520+cc]) : 0.0f; }
        break;
      }
      case 6: v = ((row<260)==(c<260)) ? -rl(P.snr2thal[row*520+c]) : 0.0f; break;
      case 7: {
        if (c < 520) { v = rl(P.thal2alm[row*520+c]); }
        else { int cc=c-520; v = rl(P.alm2alm[row*520+cc]) * ((cc<364) ? 1.0f : -1.0f); }
        break;
      }
    }
    v *= AL;
  }
  Wt[e] = v;
}

// hT[u][b] = hn[b][u]
__global__ void init_h(const float* __restrict__ hn, float* __restrict__ h0) {
  int i = blockIdx.x * blockDim.x + threadIdx.x;
  if (i < TOT * BB) {
    int u = i >> 3, b = i & 7;
    h0[i] = hn[b * TOT + u];
  }
}

__global__ void zero_bar(unsigned* __restrict__ bar) {
  if (threadIdx.x < 272) bar[threadIdx.x] = 0u;
}

// 1024 threads/WG, W in registers for all 1000 steps, custom 2-level grid barrier.
__global__ void __launch_bounds__(1024, 4)
rnn_scan(const float* __restrict__ Wt, const float* __restrict__ noise,
         const float* __restrict__ inp, float* __restrict__ out,
         float* __restrict__ h0, float* __restrict__ h1,
         unsigned* __restrict__ bar) {
  __shared__ float S[33280];   // union: h as [b][c] stride 2308 / partials [128][260]
  const int bid = blockIdx.x, tid = threadIdx.x;
  int r = 0;
  while (bid >= kWgStart[r + 1]) ++r;

  unsigned* cnt1 = bar;          // 8 groups, stride 32 words (128B apart)
  unsigned* cnt0 = bar + 256;
  unsigned* flag = bar + 257;
  const int g8   = bid & 7;
  const unsigned gsz = (g8 == 0) ? 31u : 30u;

  const int wgl     = bid - kWgStart[r];
  const int cols    = kCols[r];
  const int rowcnt  = kRowCnt[r];
  const int rowbase = kRowBase[r];
  const int rg = tid >> 8, sp = tid & 255;
  const int ugg = wgl * 4 + rg;
  const float* wtp = Wt + kWtOff[r] + (size_t)ugg * cols * 4;
  const float ton = kTonic[r];
  const int l0 = kSegLen[r][0], l1 = kSegLen[r][1];
  const int g0 = kSegStart[r][0], g1 = kSegStart[r][1], g2 = kSegStart[r][2];

  // ---- W fragment into registers (persists across all 1000 steps)
  float4 w[9];
  #pragma unroll
  for (int i = 0; i < 9; ++i) {
    int c = sp + (i << 8);
    if (c < cols) w[i] = *reinterpret_cast<const float4*>(wtp + (size_t)c * 4);
    else          w[i] = make_float4(0.f, 0.f, 0.f, 0.f);
  }

  // ---- t-invariant staging offsets (element index into hc, -1 => zero-fill)
  int goff[18];
  #pragma unroll
  for (int k2 = 0; k2 < 18; ++k2) {
    int i = tid + (k2 << 10);
    int c = i >> 3, bb = i & 7;
    int g;
    if (c < l0)           g = g0 + c;
    else if (c < l0 + l1) g = g1 + (c - l0);
    else                  g = g2 + (c - l0 - l1);
    goff[k2] = (c < cols) ? ((g << 3) + bb) : -1;
  }

  // ---- epilogue role: threads with (tid&7)==0 own output o = tid>>3 = (row,b)
  const int  j     = tid & 7;
  const int  o     = tid >> 3;          // 0..127
  const int  erow  = o >> 3, eb = o & 7;
  const int  erowl = wgl * 16 + erow;
  const bool eiti  = (r == 2) && (wgl == 9) && (j == 0) && (erowl >= 156); // ITI fold
  const bool ewr   = (j == 0) && (erowl < rowcnt);
  const int  erg   = eiti ? (3796 + (erowl - 156)) : (rowbase + erowl);
  const bool own   = ewr || eiti;

  // prefetch step-0 epilogue operands; hp is carried thereafter (own row's output)
  float hp = 0.f, nz = 0.f, ii = 0.f;
  if (own) {
    hp = h0[erg * 8 + eb];
    nz = noise[((size_t)eb * TT) * TOT + erg];
    if (eiti) ii = inp[((size_t)eb * TT) * 4 + (erg - 3796)];
  }

  for (int t = 0; t < TT; ++t) {
    const float* __restrict__ hc = (t & 1) ? h1 : h0;
    float*       __restrict__ hx = (t & 1) ? h0 : h1;

    // stage h transposed: S[b*2308 + c]
    #pragma unroll
    for (int k2 = 0; k2 < 18; ++k2) {
      int i = tid + (k2 << 10);
      int c = i >> 3, bb = i & 7;
      float v = 0.f;
      if (goff[k2] >= 0) v = hc[goff[k2]];
      S[bb * 2308 + c] = v;
    }
    __syncthreads();

    // FMA burst: 72 conflict-free ds_read_b32 + 288 fmaf per thread
    float acc[4][8];
    #pragma unroll
    for (int r2 = 0; r2 < 4; ++r2)
      #pragma unroll
      for (int b = 0; b < 8; ++b) acc[r2][b] = 0.f;

    #pragma unroll
    for (int i = 0; i < 9; ++i) {
      const float4 wv = w[i];
      const int c = sp + (i << 8);
      #pragma unroll
      for (int b = 0; b < 8; ++b) {
        const float h = S[b * 2308 + c];
        acc[0][b] = fmaf(wv.x, h, acc[0][b]);
        acc[1][b] = fmaf(wv.y, h, acc[1][b]);
        acc[2][b] = fmaf(wv.z, h, acc[2][b]);
        acc[3][b] = fmaf(wv.w, h, acc[3][b]);
      }
    }
    __syncthreads();   // done reading h; reuse S for partials

    // partials: S[((rg*4+r)*8+b)*260 + sp]
    #pragma unroll
    for (int r2 = 0; r2 < 4; ++r2)
      #pragma unroll
      for (int b = 0; b < 8; ++b)
        S[((rg * 4 + r2) * 8 + b) * 260 + sp] = acc[r2][b];
    __syncthreads();

    // reduce 256 splits: thread (o,j) sums sp = j+8k, then 3x shfl_xor over j
    float s = 0.f;
    #pragma unroll
    for (int k = 0; k < 32; ++k) s += S[o * 260 + j + (k << 3)];
    s += __shfl_xor(s, 1);
    s += __shfl_xor(s, 2);
    s += __shfl_xor(s, 4);

    float x = 0.f;
    if (eiti)     x = fmaxf(fmaf(0.9f, hp, AL * (nz + ii)), 0.0f);
    else if (ewr) x = fmaxf(fmaf(0.9f, hp, s + AL * (ton + nz)), 0.0f);
    if (own) hx[erg * 8 + eb] = x;
    __syncthreads();                       // all hx writes of this WG issued+drained

    // ---- arrive (release)
    if (tid == 0) {
      __threadfence();
      unsigned old = atomicAdd(&cnt1[g8 * 32], 1u);
      if (old + 1 == gsz * (unsigned)(t + 1)) {
        unsigned o0 = atomicAdd(cnt0, 1u);
        if (o0 + 1 == 8u * (unsigned)(t + 1)) {
          __hip_atomic_store(flag, (unsigned)(t + 1), __ATOMIC_RELEASE, __HIP_MEMORY_SCOPE_AGENT);
        }
      }
    }

    // ---- independent work hidden under the barrier: out-store + next-step prefetch
    if (own) {
      out[((size_t)eb * TT + t) * TOT + erg] = x;
      hp = x;                               // own row's h_prev for t+1
      if (t + 1 < TT) {
        nz = noise[((size_t)eb * TT + (t + 1)) * TOT + erg];
        if (eiti) ii = inp[((size_t)eb * TT + (t + 1)) * 4 + (erg - 3796)];
      }
    }

    // ---- wait (acquire)
    if (tid == 0) {
      while (__hip_atomic_load(flag, __ATOMIC_RELAXED, __HIP_MEMORY_SCOPE_AGENT) < (unsigned)(t + 1)) {}
      __threadfence();
    }
    __syncthreads();
  }
}

extern "C" void kernel_launch(void* const* d_in, const int* in_sizes, int n_in,
                              void* d_out, int out_size, void* d_ws, size_t ws_size,
                              hipStream_t stream) {
  Params P;
  P.d12d1   = (const float*)d_in[0];  P.d22d2   = (const float*)d_in[1];
  P.d12d2   = (const float*)d_in[2];  P.d22d1   = (const float*)d_in[3];
  P.thal2alm= (const float*)d_in[4];  P.thal2d1 = (const float*)d_in[5];
  P.thal2d2 = (const float*)d_in[6];  P.alm2alm = (const float*)d_in[7];
  P.alm2d1  = (const float*)d_in[8];  P.alm2d2  = (const float*)d_in[9];
  P.d12snr  = (const float*)d_in[10]; P.d22gpe  = (const float*)d_in[11];
  P.gpe2stn = (const float*)d_in[12]; P.stn2snr = (const float*)d_in[13];
  P.snr2thal= (const float*)d_in[14]; P.fsi2d1  = (const float*)d_in[15];
  P.fsi2d2  = (const float*)d_in[16]; P.thal2fsi= (const float*)d_in[17];
  P.alm2fsi = (const float*)d_in[18]; P.iti2fsi = (const float*)d_in[19];
  P.fsi2fsi = (const float*)d_in[20]; P.mask    = (const int*)d_in[21];
  const float* inp   = (const float*)d_in[22];
  const float* hn    = (const float*)d_in[23];
  const float* noise = (const float*)d_in[24];

  float* ws = (float*)d_ws;
  float* Wt = ws;
  float* h0 = ws + WT_FLOATS;
  float* h1 = h0 + TOT * BB;
  unsigned* bar = (unsigned*)(h1 + TOT * BB);

  hipLaunchKernelGGL(prep_wt,  dim3((WT_FLOATS + 255) / 256), dim3(256), 0, stream, P, Wt);
  hipLaunchKernelGGL(init_h,   dim3((TOT * BB + 255) / 256),  dim3(256), 0, stream, hn, h0);
  hipLaunchKernelGGL(zero_bar, dim3(1), dim3(512), 0, stream, bar);

  const float* WtA = Wt; const float* noiseA = noise; const float* inpA = inp;
  float* outA = (float*)d_out; float* h0A = h0; float* h1A = h1; unsigned* barA = bar;
  void* kargs[7] = {&WtA, &noiseA, &inpA, &outA, &h0A, &h1A, &barA};
  hipLaunchCooperativeKernel((const void*)rnn_scan, dim3(NWG), dim3(1024), kargs, 0, stream);
}

// Round 4
// 10123.044 us; speedup vs baseline: 5.8266x; 1.9597x over previous
//
#include <hip/hip_runtime.h>

#define TOT   3800
#define BB    8
#define TT    1000
#define AL    0.1f

constexpr int WT_FLOATS = 4475136;   // sum of padded region blocks
constexpr int NWG       = 241;       // ITI folded into FSI wg 9's padded rows

// region order: D1, D2, FSI(+ITI), GPE, STN, SNR, THAL, ALM
__constant__ int   kWgStart[9]    = {0,33,66,76,109,142,175,208,241};
__constant__ int   kRowBase[8]    = {0,520,1040,1196,1716,2236,2756,3276};
__constant__ int   kRowCnt[8]     = {520,520,156,520,520,520,520,520};
__constant__ int   kCols[8]       = {2236,2236,1200,520,520,1040,520,1040};
__constant__ int   kWtOff[8]      = {0,1180608,2361216,2553216,2827776,3102336,3651456,3926016};
__constant__ int   kWtEnd[8]      = {1180608,2361216,2553216,2827776,3102336,3651456,3926016,4475136};
__constant__ float kTonic[8]      = {0.01f,0.01f,0.01f,0.8f,0.6f,0.8f,0.01f,0.01f};
// staging segments: packed-col ranges -> global h columns
__constant__ int   kSegStart[8][3]= {{0,2756,0},{0,2756,0},{1040,2756,3796},{520,0,0},{1196,0,0},{0,1716,0},{2236,0,0},{2756,0,0}};
__constant__ int   kSegLen[8][3]  = {{1196,1040,0},{1196,1040,0},{156,1040,4},{520,0,0},{520,0,0},{520,520,0},{520,0,0},{1040,0,0}};

struct Params {
  const float *d12d1,*d22d2,*d12d2,*d22d1,*thal2alm,*thal2d1,*thal2d2,*alm2alm,
              *alm2d1,*alm2d2,*d12snr,*d22gpe,*gpe2stn,*stn2snr,*snr2thal,
              *fsi2d1,*fsi2d2,*thal2fsi,*alm2fsi,*iti2fsi,*fsi2fsi;
  const int* mask;
};

__device__ __forceinline__ float rl(float x) { return fmaxf(x, 0.0f); }

// Build packed, pre-masked, pre-signed, ALPHA-scaled W.
// Layout per region: offset = (ugg*cols + col)*4 + j, row = ugg*4 + j
__global__ void prep_wt(Params P, float* __restrict__ Wt) {
  int e = blockIdx.x * blockDim.x + threadIdx.x;
  if (e >= WT_FLOATS) return;
  int r = 0;
  while (e >= kWtEnd[r]) ++r;
  int base  = (r == 0) ? 0 : kWtEnd[r-1];
  int local = e - base;
  int j    = local & 3;
  int q    = local >> 2;
  int cols = kCols[r];
  int col  = q % cols;
  int ugg  = q / cols;
  int row  = ugg * 4 + j;
  float v = 0.0f;
  if (row < kRowCnt[r]) {
    int c = col;
    switch (r) {
      case 0: case 1: {
        const float* pd1 = (r==0) ? P.d12d1 : P.d12d2;
        const float* pd2 = (r==0) ? P.d22d1 : P.d22d2;
        const float* pf  = (r==0) ? P.fsi2d1 : P.fsi2d2;
        const float* pt  = (r==0) ? P.thal2d1 : P.thal2d2;
        const float* pa  = (r==0) ? P.alm2d1 : P.alm2d2;
        if (c < 520)       { v = -(float)P.mask[row*520+c] * rl(pd1[row*520+c]); }
        else if (c < 1040) { int cc=c-520;  v = -(float)P.mask[row*520+cc] * rl(pd2[row*520+cc]); }
        else if (c < 1196) { int cc=c-1040; v = -rl(pf[row*156+cc]); }
        else if (c < 1716) { int cc=c-1196; v =  rl(pt[row*520+cc]); }
        else               { int cc=c-1716; v = (cc<364) ? rl(pa[row*520+cc]) : 0.0f; }
        break;
      }
      case 2: {
        if (c < 156)       { v = -rl(P.fsi2fsi[row*156+c]); }
        else if (c < 676)  { int cc=c-156; v = rl(P.thal2fsi[row*520+cc]); }
        else if (c < 1196) { int cc=c-676; v = (cc<364) ? rl(P.alm2fsi[row*520+cc]) : 0.0f; }
        else               { int cc=c-1196; v = rl(P.iti2fsi[row*4+cc]); }
        break;
      }
      case 3: v = ((row<260)==(c<260)) ? -rl(P.d22gpe[row*520+c])  : 0.0f; break;
      case 4: v = ((row<260)==(c<260)) ? -rl(P.gpe2stn[row*520+c]) : 0.0f; break;
      case 5: {
        if (c < 520) { v = ((row<260)==(c<260)) ? -rl(P.d12snr[row*520+c]) : 0.0f; }
        else { int cc=c-520; v = ((row<260)==(cc<260)) ? rl(P.stn2snr[row*520+cc]) : 0.0f; }
        break;
      }
      case 6: v = ((row<260)==(c<260)) ? -rl(P.snr2thal[row*520+c]) : 0.0f; break;
      case 7: {
        if (c < 520) { v = rl(P.thal2alm[row*520+c]); }
        else { int cc=c-520; v = rl(P.alm2alm[row*520+cc]) * ((cc<364) ? 1.0f : -1.0f); }
        break;
      }
    }
    v *= AL;
  }
  Wt[e] = v;
}

// hT[u][b] = hn[b][u]
__global__ void init_h(const float* __restrict__ hn, float* __restrict__ h0) {
  int i = blockIdx.x * blockDim.x + threadIdx.x;
  if (i < TOT * BB) {
    int u = i >> 3, b = i & 7;
    h0[i] = hn[b * TOT + u];
  }
}

__global__ void zero_bar(unsigned* __restrict__ bar) {
  if (threadIdx.x < 272) bar[threadIdx.x] = 0u;
}

__device__ __forceinline__ float ag_load(const float* p) {
  return __hip_atomic_load(p, __ATOMIC_RELAXED, __HIP_MEMORY_SCOPE_AGENT);
}
__device__ __forceinline__ void ag_store(float* p, float v) {
  __hip_atomic_store(p, v, __ATOMIC_RELAXED, __HIP_MEMORY_SCOPE_AGENT);
}

// 1024 threads/WG, W in registers for all 1000 steps.
// All cross-WG state (h ping-pong, barrier words) is agent-scope (sc0/sc1,
// LLC-coherent) -> no __threadfence, no per-step L2 writeback/invalidate.
__global__ void __launch_bounds__(1024, 4)
rnn_scan(const float* __restrict__ Wt, const float* __restrict__ noise,
         const float* __restrict__ inp, float* __restrict__ out,
         float* __restrict__ h0, float* __restrict__ h1,
         unsigned* __restrict__ bar) {
  __shared__ float S[33280];   // union: h as [b][c] stride 2308 / partials [128][260]
  const int bid = blockIdx.x, tid = threadIdx.x;
  int r = 0;
  while (bid >= kWgStart[r + 1]) ++r;

  unsigned* cnt1 = bar;          // 8 groups, stride 32 words (128B apart)
  unsigned* cnt0 = bar + 256;
  unsigned* flag = bar + 257;
  const int g8   = bid & 7;
  const unsigned gsz = (g8 == 0) ? 31u : 30u;

  const int wgl     = bid - kWgStart[r];
  const int cols    = kCols[r];
  const int rowcnt  = kRowCnt[r];
  const int rowbase = kRowBase[r];
  const int rg = tid >> 8, sp = tid & 255;
  const int ugg = wgl * 4 + rg;
  const float* wtp = Wt + kWtOff[r] + (size_t)ugg * cols * 4;
  const float ton = kTonic[r];
  const int l0 = kSegLen[r][0], l1 = kSegLen[r][1];
  const int g0 = kSegStart[r][0], g1 = kSegStart[r][1], g2 = kSegStart[r][2];

  // ---- W fragment into registers (persists across all 1000 steps)
  float4 w[9];
  #pragma unroll
  for (int i = 0; i < 9; ++i) {
    int c = sp + (i << 8);
    if (c < cols) w[i] = *reinterpret_cast<const float4*>(wtp + (size_t)c * 4);
    else          w[i] = make_float4(0.f, 0.f, 0.f, 0.f);
  }

  // ---- t-invariant staging offsets (element index into hc, -1 => zero-fill)
  int goff[18];
  #pragma unroll
  for (int k2 = 0; k2 < 18; ++k2) {
    int i = tid + (k2 << 10);
    int c = i >> 3, bb = i & 7;
    int g;
    if (c < l0)           g = g0 + c;
    else if (c < l0 + l1) g = g1 + (c - l0);
    else                  g = g2 + (c - l0 - l1);
    goff[k2] = (c < cols) ? ((g << 3) + bb) : -1;
  }

  // ---- epilogue role: threads with (tid&7)==0 own output o = tid>>3 = (row,b)
  const int  j     = tid & 7;
  const int  o     = tid >> 3;          // 0..127
  const int  erow  = o >> 3, eb = o & 7;
  const int  erowl = wgl * 16 + erow;
  const bool eiti  = (r == 2) && (wgl == 9) && (j == 0) && (erowl >= 156); // ITI fold
  const bool ewr   = (j == 0) && (erowl < rowcnt);
  const int  erg   = eiti ? (3796 + (erowl - 156)) : (rowbase + erowl);
  const bool own   = ewr || eiti;

  // prefetch step-0 epilogue operands; hp is carried thereafter (own row's output)
  float hp = 0.f, nz = 0.f, ii = 0.f;
  if (own) {
    hp = h0[erg * 8 + eb];
    nz = noise[((size_t)eb * TT) * TOT + erg];
    if (eiti) ii = inp[((size_t)eb * TT) * 4 + (erg - 3796)];
  }

  for (int t = 0; t < TT; ++t) {
    const float* __restrict__ hc = (t & 1) ? h1 : h0;
    float*       __restrict__ hx = (t & 1) ? h0 : h1;

    // stage h transposed: S[b*2308 + c]  (agent-scope loads, always LLC-fresh)
    #pragma unroll
    for (int k2 = 0; k2 < 18; ++k2) {
      int i = tid + (k2 << 10);
      int c = i >> 3, bb = i & 7;
      float v = 0.f;
      if (goff[k2] >= 0) v = ag_load(&hc[goff[k2]]);
      S[bb * 2308 + c] = v;
    }
    __syncthreads();

    // FMA burst: 72 conflict-free ds_read_b32 + 288 fmaf per thread
    float acc[4][8];
    #pragma unroll
    for (int r2 = 0; r2 < 4; ++r2)
      #pragma unroll
      for (int b = 0; b < 8; ++b) acc[r2][b] = 0.f;

    #pragma unroll
    for (int i = 0; i < 9; ++i) {
      const float4 wv = w[i];
      const int c = sp + (i << 8);
      #pragma unroll
      for (int b = 0; b < 8; ++b) {
        const float h = S[b * 2308 + c];
        acc[0][b] = fmaf(wv.x, h, acc[0][b]);
        acc[1][b] = fmaf(wv.y, h, acc[1][b]);
        acc[2][b] = fmaf(wv.z, h, acc[2][b]);
        acc[3][b] = fmaf(wv.w, h, acc[3][b]);
      }
    }
    __syncthreads();   // done reading h; reuse S for partials

    // partials: S[((rg*4+r)*8+b)*260 + sp]
    #pragma unroll
    for (int r2 = 0; r2 < 4; ++r2)
      #pragma unroll
      for (int b = 0; b < 8; ++b)
        S[((rg * 4 + r2) * 8 + b) * 260 + sp] = acc[r2][b];
    __syncthreads();

    // reduce 256 splits: thread (o,j) sums sp = j+8k, then 3x shfl_xor over j
    float s = 0.f;
    #pragma unroll
    for (int k = 0; k < 32; ++k) s += S[o * 260 + j + (k << 3)];
    s += __shfl_xor(s, 1);
    s += __shfl_xor(s, 2);
    s += __shfl_xor(s, 4);

    float x = 0.f;
    if (eiti)     x = fmaxf(fmaf(0.9f, hp, AL * (nz + ii)), 0.0f);
    else if (ewr) x = fmaxf(fmaf(0.9f, hp, s + AL * (ton + nz)), 0.0f);
    if (own) ag_store(&hx[erg * 8 + eb], x);   // LLC write-through, no L2 dirty line
    __syncthreads();   // compiler drains vmcnt(0) per wave -> all hx acked at LLC

    // ---- arrive (no cache maintenance needed: all shared data is sc1)
    if (tid == 0) {
      unsigned old = atomicAdd(&cnt1[g8 * 32], 1u);
      if (old + 1 == gsz * (unsigned)(t + 1)) {
        unsigned o0 = atomicAdd(cnt0, 1u);
        if (o0 + 1 == 8u * (unsigned)(t + 1)) {
          __hip_atomic_store(flag, (unsigned)(t + 1), __ATOMIC_RELAXED, __HIP_MEMORY_SCOPE_AGENT);
        }
      }
    }

    // ---- independent work hidden under the barrier: out-store + next-step prefetch
    if (own) {
      out[((size_t)eb * TT + t) * TOT + erg] = x;
      hp = x;                               // own row's h_prev for t+1
      if (t + 1 < TT) {
        nz = noise[((size_t)eb * TT + (t + 1)) * TOT + erg];
        if (eiti) ii = inp[((size_t)eb * TT + (t + 1)) * 4 + (erg - 3796)];
      }
    }

    // ---- wait
    if (tid == 0) {
      while (__hip_atomic_load(flag, __ATOMIC_RELAXED, __HIP_MEMORY_SCOPE_AGENT) < (unsigned)(t + 1)) {}
    }
    __syncthreads();
  }
}

extern "C" void kernel_launch(void* const* d_in, const int* in_sizes, int n_in,
                              void* d_out, int out_size, void* d_ws, size_t ws_size,
                              hipStream_t stream) {
  Params P;
  P.d12d1   = (const float*)d_in[0];  P.d22d2   = (const float*)d_in[1];
  P.d12d2   = (const float*)d_in[2];  P.d22d1   = (const float*)d_in[3];
  P.thal2alm= (const float*)d_in[4];  P.thal2d1 = (const float*)d_in[5];
  P.thal2d2 = (const float*)d_in[6];  P.alm2alm = (const float*)d_in[7];
  P.alm2d1  = (const float*)d_in[8];  P.alm2d2  = (const float*)d_in[9];
  P.d12snr  = (const float*)d_in[10]; P.d22gpe  = (const float*)d_in[11];
  P.gpe2stn = (const float*)d_in[12]; P.stn2snr = (const float*)d_in[13];
  P.snr2thal= (const float*)d_in[14]; P.fsi2d1  = (const float*)d_in[15];
  P.fsi2d2  = (const float*)d_in[16]; P.thal2fsi= (const float*)d_in[17];
  P.alm2fsi = (const float*)d_in[18]; P.iti2fsi = (const float*)d_in[19];
  P.fsi2fsi = (const float*)d_in[20]; P.mask    = (const int*)d_in[21];
  const float* inp   = (const float*)d_in[22];
  const float* hn    = (const float*)d_in[23];
  const float* noise = (const float*)d_in[24];

  float* ws = (float*)d_ws;
  float* Wt = ws;
  float* h0 = ws + WT_FLOATS;
  float* h1 = h0 + TOT * BB;
  unsigned* bar = (unsigned*)(h1 + TOT * BB);

  hipLaunchKernelGGL(prep_wt,  dim3((WT_FLOATS + 255) / 256), dim3(256), 0, stream, P, Wt);
  hipLaunchKernelGGL(init_h,   dim3((TOT * BB + 255) / 256),  dim3(256), 0, stream, hn, h0);
  hipLaunchKernelGGL(zero_bar, dim3(1), dim3(512), 0, stream, bar);

  const float* WtA = Wt; const float* noiseA = noise; const float* inpA = inp;
  float* outA = (float*)d_out; float* h0A = h0; float* h1A = h1; unsigned* barA = bar;
  void* kargs[7] = {&WtA, &noiseA, &inpA, &outA, &h0A, &h1A, &barA};
  hipLaunchCooperativeKernel((const void*)rnn_scan, dim3(NWG), dim3(1024), kargs, 0, stream);
}